// Round 1
// baseline (667.041 us; speedup 1.0000x reference)
//
#include <hip/hip_runtime.h>

// out = -weight * sum(factor[1:] * factor[:-1]) / (N-1),  factor (65536, 2000) fp32.
//
// Round 4: wave-sequential streaming. Dispatch-stream arithmetic on the rocprof
// table (Dispatch_Id = 2*ord+4; fill ords 46,49,58,118,214, gaps all % 3 == 0)
// shows the timed window is {2GB ws-poison fill (333us, harness), 4B memset,
// kernel} => kernel ~= 325us ~= 1.6 TB/s, 4x off the 6.3 TB/s read ceiling
// despite exactly-once traffic.
//
// Round 3's walker was the thread-column: each wave read a 1 KB strip at 8 KB
// stride, 65 short hops -- every wave-load opens a fresh DRAM page, no stream
// is ever sequential beyond 1 KB. This round makes the WAVE the row-walker:
// each wave owns 16 consecutive rows and streams them purely sequentially
// (8 x dwordx4 per 8000 B row, rows back-to-back = one contiguous 136 KB
// stream per wave), carrying the previous row's fragment (8 float4/lane) in
// registers so every element is still read from HBM exactly once (+1 halo row
// per 16-row band = 6.25% overfetch, ~557 MB total).
//
// 512 blocks x 512 threads = 4096 walker waves; 2 blocks/CU = 16 waves/CU.
// Row tail: 500 float4 = 7*64 + 52, so fragment p=7 lives only on lanes 0..51
// (predicated; lanes 52..63 contribute 0 and still join the shuffle reduce).

#define N_ROWS   65536
#define D_COLS   2000
#define ROW4     (D_COLS / 4)          // 500 float4 per row (8000 B)
#define NTHREADS 512
#define NBLOCKS  512
#define WPB      (NTHREADS / 64)       // 8 waves per block
#define NWAVES   (NBLOCKS * WPB)       // 4096 walker waves
#define BAND     (N_ROWS / NWAVES)     // 16 product-rows per wave

__global__ __launch_bounds__(NTHREADS) void shifted_dot_wavestream(
    const float* __restrict__ a,
    const float* __restrict__ weight,
    float* __restrict__ out) {
    const int lane = threadIdx.x & 63;
    const int wid  = threadIdx.x >> 6;
    const int w    = blockIdx.x * WPB + wid;

    const long long r0 = (long long)w * BAND;   // first product row of this wave
    long long r1 = r0 + BAND;                   // products n in [r0, r1)
    if (r1 > N_ROWS - 1) r1 = N_ROWS - 1;       // last wave: BAND-1 products

    // lane's fragments of a row: float4 indices p*64+lane, p=0..7 (p=7: lanes<52)
    const float4* row = (const float4*)a + r0 * ROW4;
    const bool tail = (lane < 52);

    float4 prev[8];
    #pragma unroll
    for (int p = 0; p < 7; ++p) prev[p] = row[p * 64 + lane];
    if (tail) prev[7] = row[448 + lane];

    float4 acc = make_float4(0.f, 0.f, 0.f, 0.f);

    #pragma unroll 2
    for (long long n = r0; n < r1; ++n) {
        row += ROW4;                            // row n+1 (sequential stream)
        float4 c[7];
        #pragma unroll
        for (int p = 0; p < 7; ++p) c[p] = row[p * 64 + lane];
        float4 c7;
        if (tail) c7 = row[448 + lane];         // issue load before the FMA block

        #pragma unroll
        for (int p = 0; p < 7; ++p) {
            acc.x += prev[p].x * c[p].x;
            acc.y += prev[p].y * c[p].y;
            acc.z += prev[p].z * c[p].z;
            acc.w += prev[p].w * c[p].w;
            prev[p] = c[p];
        }
        if (tail) {
            acc.x += prev[7].x * c7.x;
            acc.y += prev[7].y * c7.y;
            acc.z += prev[7].z * c7.z;
            acc.w += prev[7].w * c7.w;
            prev[7] = c7;
        }
    }

    float s = acc.x + acc.y + acc.z + acc.w;

    // wave (64-lane) shuffle reduction
    #pragma unroll
    for (int off = 32; off > 0; off >>= 1)
        s += __shfl_down(s, off, 64);

    __shared__ float wave_sums[WPB];
    if (lane == 0) wave_sums[wid] = s;
    __syncthreads();

    if (threadIdx.x == 0) {
        float tot = 0.f;
        #pragma unroll
        for (int i = 0; i < WPB; ++i) tot += wave_sums[i];
        float wgt = weight[0];
        atomicAdd(out, tot * (-wgt / (float)(N_ROWS - 1)));
    }
}

extern "C" void kernel_launch(void* const* d_in, const int* in_sizes, int n_in,
                              void* d_out, int out_size, void* d_ws, size_t ws_size,
                              hipStream_t stream) {
    const float* factor = (const float*)d_in[0];
    const float* weight = (const float*)d_in[1];
    float* out = (float*)d_out;

    // d_out is poisoned to 0xAA before every call; zero it (async, capture-safe).
    hipMemsetAsync(out, 0, sizeof(float), stream);

    dim3 grid(NBLOCKS), block(NTHREADS);
    shifted_dot_wavestream<<<grid, block, 0, stream>>>(factor, weight, out);
}

// Round 2
// 637.426 us; speedup vs baseline: 1.0465x; 1.0465x over previous
//
#include <hip/hip_runtime.h>

// out = -weight * sum(factor[1:] * factor[:-1]) / (N-1),  factor (65536, 2000) fp32.
//
// Round 5: nontemporal + explicit 2-row pipeline.
// Evidence so far: round-3 (strided column walker) and round-4 (sequential
// 136KB wave streams) both give dur_us = 665-667 (+0.3%). Little's-law check:
// 16 waves/CU x 8KB in flight => ~170 GB/s/CU sustainable >> 24.6 GB/s/CU
// needed at peak, so the kernel cannot be latency-bound at ~330us; dur_us is
// likely dominated by harness fixed costs (2GB ws-poison fill = 330us measured,
// + probable input-restore copy ~155us hiding below the top-5 cutoff).
// Remaining kernel-side suspect: cache-allocation churn (512MB stream > 256MB
// L3, every load allocates/evicts). Fix: nontemporal loads (nt flag, no cache
// allocation) + explicit 2-row software pipeline (16 loads in flight, dual
// accumulators). If dur_us doesn't move again, the fixed-cost story is
// confirmed and the kernel is at its roofline.
//
// Layout: row = 2000 f32 = 500 float4 (8000B, rows 16B-aligned). Each wave
// owns BAND=16 product rows, streams rows sequentially (8x dwordx4 = 8KB
// contiguous per row), carries prev row in registers => each element read
// exactly once (+1 halo row per band = 6.25%, ~557MB total).
// 1024 blocks x 256 thr = 4096 waves; ~116 VGPR -> 4 waves/SIMD = 16 waves/CU.

#define N_ROWS   65536
#define D_COLS   2000
#define ROW4     (D_COLS / 4)      // 500 float4 per row
#define NTHREADS 256
#define NBLOCKS  1024
#define WPB      (NTHREADS / 64)   // 4 waves per block
#define NWAVES   (NBLOCKS * WPB)   // 4096 walker waves
#define BAND     (N_ROWS / NWAVES) // 16 product-rows per wave

typedef float f32x4 __attribute__((ext_vector_type(4)));

__device__ __forceinline__ f32x4 ntload(const f32x4* p) {
    return __builtin_nontemporal_load(p);
}

__global__ __launch_bounds__(NTHREADS) void shifted_dot_ntpipe(
    const float* __restrict__ a,
    const float* __restrict__ weight,
    float* __restrict__ out) {
    const int lane = threadIdx.x & 63;
    const int wid  = threadIdx.x >> 6;
    const int w    = blockIdx.x * WPB + wid;

    const long long r0 = (long long)w * BAND;  // first product row
    long long r1 = r0 + BAND;                  // products n in [r0, r1)
    if (r1 > N_ROWS - 1) r1 = N_ROWS - 1;

    // lane's fragments: float4 index p*64+lane, p=0..6; p=7 only lanes 0..51
    const f32x4* row = (const f32x4*)a + r0 * ROW4;
    const bool tail = (lane < 52);

    f32x4 prev[8];
    #pragma unroll
    for (int p = 0; p < 7; ++p) prev[p] = ntload(row + p * 64 + lane);
    prev[7] = (f32x4)(0.f);
    if (tail) prev[7] = ntload(row + 448 + lane);

    f32x4 accA = (f32x4)(0.f);
    f32x4 accB = (f32x4)(0.f);

    long long n = r0;
    // 2-row software pipeline: issue all 16 loads, then both FMA blocks.
    for (; n + 2 <= r1; n += 2) {
        const f32x4* rowA = row + ROW4;
        const f32x4* rowB = row + 2 * ROW4;

        f32x4 cA[8], cB[8];
        #pragma unroll
        for (int p = 0; p < 7; ++p) cA[p] = ntload(rowA + p * 64 + lane);
        if (tail) cA[7] = ntload(rowA + 448 + lane);
        #pragma unroll
        for (int p = 0; p < 7; ++p) cB[p] = ntload(rowB + p * 64 + lane);
        if (tail) cB[7] = ntload(rowB + 448 + lane);

        #pragma unroll
        for (int p = 0; p < 7; ++p) {
            accA += prev[p] * cA[p];
            accB += cA[p] * cB[p];
            prev[p] = cB[p];
        }
        if (tail) {
            accA += prev[7] * cA[7];
            accB += cA[7] * cB[7];
            prev[7] = cB[7];
        }
        row = rowB;
    }
    if (n < r1) {  // odd leftover product
        const f32x4* rowA = row + ROW4;
        f32x4 cA[8];
        #pragma unroll
        for (int p = 0; p < 7; ++p) cA[p] = ntload(rowA + p * 64 + lane);
        #pragma unroll
        for (int p = 0; p < 7; ++p) accA += prev[p] * cA[p];
        if (tail) {
            f32x4 c7 = ntload(rowA + 448 + lane);
            accA += prev[7] * c7;
        }
    }

    f32x4 acc = accA + accB;
    float s = acc[0] + acc[1] + acc[2] + acc[3];

    // wave shuffle reduction (64 lanes)
    #pragma unroll
    for (int off = 32; off > 0; off >>= 1)
        s += __shfl_down(s, off, 64);

    __shared__ float wave_sums[WPB];
    if (lane == 0) wave_sums[wid] = s;
    __syncthreads();

    if (threadIdx.x == 0) {
        float tot = 0.f;
        #pragma unroll
        for (int i = 0; i < WPB; ++i) tot += wave_sums[i];
        float wgt = weight[0];
        atomicAdd(out, tot * (-wgt / (float)(N_ROWS - 1)));
    }
}

extern "C" void kernel_launch(void* const* d_in, const int* in_sizes, int n_in,
                              void* d_out, int out_size, void* d_ws, size_t ws_size,
                              hipStream_t stream) {
    const float* factor = (const float*)d_in[0];
    const float* weight = (const float*)d_in[1];
    float* out = (float*)d_out;

    // d_out is poisoned to 0xAA before every call; zero it (async, capture-safe).
    hipMemsetAsync(out, 0, sizeof(float), stream);

    dim3 grid(NBLOCKS), block(NTHREADS);
    shifted_dot_ntpipe<<<grid, block, 0, stream>>>(factor, weight, out);
}